// Round 12
// baseline (2106.857 us; speedup 1.0000x reference)
//
#include <hip/hip_runtime.h>

typedef unsigned short u16;

#define RN  128   // nodes per coarse bucket
#define RSH 7
#define CAP 6400  // max records per coarse bucket staged in LDS (mean ~2560)
#define NBINS_MAX 4096

__device__ __forceinline__ float bf2f(u16 u) {
    return __uint_as_float(((unsigned int)u) << 16);
}
__device__ __forceinline__ u16 f2bf(float f) {
    unsigned int x = __float_as_uint(f);
    return (u16)((x + 0x7fffu + ((x >> 16) & 1u)) >> 16);
}

// =============== on-device weight prep (algebraic collapse) ===============
__device__ __forceinline__ void mm64(const float* A, const float* B, float* C, int lane)
{
    float bcol[64];
#pragma unroll
    for (int m = 0; m < 64; ++m) bcol[m] = B[m*64 + lane];
    for (int k = 0; k < 64; ++k) {
        float acc = 0.f;
#pragma unroll
        for (int m = 0; m < 64; ++m) acc = fmaf(A[k*64 + m], bcol[m], acc);
        C[k*64 + lane] = acc;
    }
}

__device__ __forceinline__ void vm64(const float* a, const float* B, const float* add,
                                     float* c, int lane)
{
    float acc = (add != 0) ? add[lane] : 0.f;
#pragma unroll
    for (int m = 0; m < 64; ++m) acc = fmaf(a[m], B[m*64 + lane], acc);
    c[lane] = acc;
}

__global__ __launch_bounds__(256) void prep_kernel(
    const float* vc_fw, const float* vc_fb, const float* vc_ow0,
    const float* vc_ow1, const float* vc_ob1,
    const float* cv_rw, const float* cv_fw, const float* cv_fb,
    const float* cv_ow0, const float* cv_ow1, const float* cv_ob1,
    const float* pw0, const float* pb0, const float* vhw0, const float* vhb0,
    float* Fc, float* gc, float* Hc, float* hc, float* Fv, float* gv,
    float* Pw, float* pbp, float* Vw, float* vbp)
{
    const int wv = threadIdx.x >> 6;
    const int lane = threadIdx.x & 63;
    if (wv == 0) {
        mm64(vc_fw, vc_ow0, Fc, lane);
        vm64(vc_fb, vc_ow0, 0, gc, lane);
    } else if (wv == 1) {
        mm64(vc_ow1, cv_rw, Hc, lane);
        vm64(vc_ob1, cv_rw, 0, hc, lane);
    } else if (wv == 2) {
        mm64(cv_fw, cv_ow0, Fv, lane);
        vm64(cv_fb, cv_ow0, 0, gv, lane);
    } else {
        mm64(cv_ow1, pw0, Pw, lane);
        vm64(cv_ob1, pw0, pb0, pbp, lane);
        mm64(cv_ow1, vhw0, Vw, lane);
        vm64(cv_ob1, vhw0, vhb0, vbp, lane);
    }
}

// =============== embeddings (fused with downstream per-node linears) ===============
__global__ __launch_bounds__(256) void embc_kernel(
    const float* __restrict__ X,
    const float* __restrict__ W0, const float* __restrict__ B0,
    const float* __restrict__ W1, const float* __restrict__ B1,
    const float* __restrict__ LW, const float* __restrict__ LB,
    u16* __restrict__ c0out, float* __restrict__ RlOut, int M)
{
    const int lane = threadIdx.x & 63;
    const int wv   = threadIdx.x >> 6;
    __shared__ __align__(16) float xs[4][8*5];
    __shared__ __align__(16) float hb[4][8][64];
    __shared__ __align__(16) float yb[4][8][64];
    const int rowTile = (blockIdx.x*4 + wv)*8;

    for (int idx = lane; idx < 8*5; idx += 64) {
        long gi = (long)rowTile*5 + idx;
        xs[wv][idx] = (gi < (long)M*5) ? X[gi] : 0.f;
    }
    {
        float w0[5];
#pragma unroll
        for (int k = 0; k < 5; ++k) w0[k] = W0[k*64 + lane];
        const float b0 = B0[lane];
#pragma unroll
        for (int r = 0; r < 8; ++r) {
            float acc = b0;
#pragma unroll
            for (int k = 0; k < 5; ++k) acc = fmaf(xs[wv][r*5 + k], w0[k], acc);
            hb[wv][r][lane] = fmaxf(acc, 0.f);
        }
    }
    {
        float w1[64];
#pragma unroll
        for (int k = 0; k < 64; ++k) w1[k] = W1[k*64 + lane];
        const float b1 = B1[lane];
#pragma unroll
        for (int r = 0; r < 8; ++r) {
            float acc = b1;
#pragma unroll
            for (int k4 = 0; k4 < 16; ++k4) {
                float4 h4 = *(const float4*)&hb[wv][r][k4*4];
                acc = fmaf(h4.x, w1[k4*4+0], acc);
                acc = fmaf(h4.y, w1[k4*4+1], acc);
                acc = fmaf(h4.z, w1[k4*4+2], acc);
                acc = fmaf(h4.w, w1[k4*4+3], acc);
            }
            float y = fmaxf(acc, 0.f);
            yb[wv][r][lane] = y;
            int row = rowTile + r;
            if (row < M) c0out[(size_t)row*64 + lane] = f2bf(y);
        }
    }
    {
        float w[64];
#pragma unroll
        for (int k = 0; k < 64; ++k) w[k] = LW[k*64 + lane];
        const float bb = LB[lane];
#pragma unroll
        for (int r = 0; r < 8; ++r) {
            float acc = bb;
#pragma unroll
            for (int k4 = 0; k4 < 16; ++k4) {
                float4 y4 = *(const float4*)&yb[wv][r][k4*4];
                acc = fmaf(y4.x, w[k4*4+0], acc);
                acc = fmaf(y4.y, w[k4*4+1], acc);
                acc = fmaf(y4.z, w[k4*4+2], acc);
                acc = fmaf(y4.w, w[k4*4+3], acc);
            }
            int row = rowTile + r;
            if (row < M) RlOut[(size_t)row*64 + lane] = acc;
        }
    }
}

__global__ __launch_bounds__(256) void embv_kernel(
    const float* __restrict__ X,
    const float* __restrict__ W0, const float* __restrict__ B0,
    const float* __restrict__ W1, const float* __restrict__ B1,
    const float* __restrict__ RW,
    const float* __restrict__ LW, const float* __restrict__ LB,
    u16* __restrict__ v0out, u16* __restrict__ LsOut,
    float* __restrict__ RlOut, int M)
{
    const int lane = threadIdx.x & 63;
    const int wv   = threadIdx.x >> 6;
    __shared__ __align__(16) float xs[4][8*19];
    __shared__ __align__(16) float hb[4][8][64];
    __shared__ __align__(16) float yb[4][8][64];
    const int rowTile = (blockIdx.x*4 + wv)*8;

    for (int idx = lane; idx < 8*19; idx += 64) {
        long gi = (long)rowTile*19 + idx;
        xs[wv][idx] = (gi < (long)M*19) ? X[gi] : 0.f;
    }
    {
        float w0[19];
#pragma unroll
        for (int k = 0; k < 19; ++k) w0[k] = W0[k*64 + lane];
        const float b0 = B0[lane];
#pragma unroll
        for (int r = 0; r < 8; ++r) {
            float acc = b0;
#pragma unroll
            for (int k = 0; k < 19; ++k) acc = fmaf(xs[wv][r*19 + k], w0[k], acc);
            hb[wv][r][lane] = fmaxf(acc, 0.f);
        }
    }
    {
        float w1[64];
#pragma unroll
        for (int k = 0; k < 64; ++k) w1[k] = W1[k*64 + lane];
        const float b1 = B1[lane];
#pragma unroll
        for (int r = 0; r < 8; ++r) {
            float acc = b1;
#pragma unroll
            for (int k4 = 0; k4 < 16; ++k4) {
                float4 h4 = *(const float4*)&hb[wv][r][k4*4];
                acc = fmaf(h4.x, w1[k4*4+0], acc);
                acc = fmaf(h4.y, w1[k4*4+1], acc);
                acc = fmaf(h4.z, w1[k4*4+2], acc);
                acc = fmaf(h4.w, w1[k4*4+3], acc);
            }
            float y = fmaxf(acc, 0.f);
            yb[wv][r][lane] = y;
            int row = rowTile + r;
            if (row < M) v0out[(size_t)row*64 + lane] = f2bf(y);
        }
    }
    {
        float w[64];
#pragma unroll
        for (int k = 0; k < 64; ++k) w[k] = RW[k*64 + lane];
#pragma unroll
        for (int r = 0; r < 8; ++r) {
            float acc = 0.f;
#pragma unroll
            for (int k4 = 0; k4 < 16; ++k4) {
                float4 y4 = *(const float4*)&yb[wv][r][k4*4];
                acc = fmaf(y4.x, w[k4*4+0], acc);
                acc = fmaf(y4.y, w[k4*4+1], acc);
                acc = fmaf(y4.z, w[k4*4+2], acc);
                acc = fmaf(y4.w, w[k4*4+3], acc);
            }
            int row = rowTile + r;
            if (row < M) LsOut[(size_t)row*64 + lane] = f2bf(acc);
        }
    }
    {
        float w[64];
#pragma unroll
        for (int k = 0; k < 64; ++k) w[k] = LW[k*64 + lane];
        const float bb = LB[lane];
#pragma unroll
        for (int r = 0; r < 8; ++r) {
            float acc = bb;
#pragma unroll
            for (int k4 = 0; k4 < 16; ++k4) {
                float4 y4 = *(const float4*)&yb[wv][r][k4*4];
                acc = fmaf(y4.x, w[k4*4+0], acc);
                acc = fmaf(y4.y, w[k4*4+1], acc);
                acc = fmaf(y4.z, w[k4*4+2], acc);
                acc = fmaf(y4.w, w[k4*4+3], acc);
            }
            int row = rowTile + r;
            if (row < M) RlOut[(size_t)row*64 + lane] = acc;
        }
    }
}

// =============== per-node degree histogram ===============
__global__ __launch_bounds__(256) void hist2_kernel(
    const int* __restrict__ eic, const int* __restrict__ eiv,
    int* cntC, int* cntV, int E)
{
    int e = blockIdx.x*256 + threadIdx.x;
    if (e >= E) return;
    atomicAdd(&cntC[eic[e]], 1);
    atomicAdd(&cntV[eiv[e]], 1);
}

// =============== coarse-bucket offsets (one block per direction) ===============
__global__ __launch_bounds__(256) void coarse_kernel(
    const int* __restrict__ cnt, int N, int nb, int* cOff, int* cur)
{
    __shared__ int cs[2049];
    for (int i = threadIdx.x; i < nb; i += 256) {
        int s = 0;
        int basei = i << RSH;
        int lim = N - basei; if (lim > RN) lim = RN;
        for (int j = 0; j < lim; ++j) s += cnt[basei + j];
        cs[i] = s;
    }
    __syncthreads();
    if (threadIdx.x == 0) {
        int a = 0;
        for (int i = 0; i < nb; ++i) { int t = cs[i]; cs[i] = a; a += t; }
        cs[nb] = a;
    }
    __syncthreads();
    for (int i = threadIdx.x; i < nb; i += 256) { cOff[i] = cs[i]; cur[i] = cs[i]; }
    if (threadIdx.x == 0) cOff[nb] = cs[nb];
}

// =============== block-local two-pass binned scatter ===============
__global__ __launch_bounds__(256) void binscatter_kernel(
    const int* __restrict__ eic, const int* __restrict__ eiv,
    const float* __restrict__ ef,
    int* curC, int* curV,
    uint2* __restrict__ bC, uint2* __restrict__ bV,
    int nbC, int nbV, int E)
{
    __shared__ int bins[NBINS_MAX];
    const int nb = nbC + nbV;
    const int chunk = (E + (int)gridDim.x - 1) / (int)gridDim.x;
    const int e0 = blockIdx.x * chunk;
    int e1 = e0 + chunk; if (e1 > E) e1 = E;

    for (int i = threadIdx.x; i < nb; i += 256) bins[i] = 0;
    __syncthreads();

    for (int e = e0 + threadIdx.x; e < e1; e += 256) {
        atomicAdd(&bins[eic[e] >> RSH], 1);
        atomicAdd(&bins[nbC + (eiv[e] >> RSH)], 1);
    }
    __syncthreads();

    for (int i = threadIdx.x; i < nbC; i += 256) {
        int c = bins[i];
        bins[i] = (c > 0) ? atomicAdd(&curC[i], c) : 0;
    }
    for (int i = threadIdx.x; i < nbV; i += 256) {
        int c = bins[nbC + i];
        bins[nbC + i] = (c > 0) ? atomicAdd(&curV[i], c) : 0;
    }
    __syncthreads();

    for (int e = e0 + threadIdx.x; e < e1; e += 256) {
        const int c = eic[e], v = eiv[e];
        const unsigned fb = __float_as_uint(ef[e]) & 0xFFFFFF80u;
        int pc = atomicAdd(&bins[c >> RSH], 1);
        bC[pc] = make_uint2((unsigned)v, fb | (unsigned)(c & (RN - 1)));
        int pv = atomicAdd(&bins[nbC + (v >> RSH)], 1);
        bV[pv] = make_uint2((unsigned)c, fb | (unsigned)(v & (RN - 1)));
    }
}

// =============== fused in-LDS counting sort + per-node aggregation ===============
__global__ __launch_bounds__(256) void aggsort_kernel(
    const int* __restrict__ cOff, const uint2* __restrict__ bucket,
    float* RlA, const u16* __restrict__ Lsb,
    const float* __restrict__ ew, int N)
{
    const int b = blockIdx.x;
    const int lane = threadIdx.x & 63;
    const int wv   = threadIdx.x >> 6;
    const int n0 = b << RSH;
    int nn = N - n0; if (nn > RN) nn = RN;

    __shared__ uint2 recS[CAP];
    __shared__ int cntS[RN];
    __shared__ int offS[RN + 1];

    const int e0 = cOff[b];
    int ec = cOff[b + 1] - e0;
    if (ec > CAP) ec = CAP;

    for (int i = threadIdx.x; i < RN; i += 256) cntS[i] = 0;
    __syncthreads();
    for (int i = threadIdx.x; i < ec; i += 256) {
        uint2 q = bucket[e0 + i];
        atomicAdd(&cntS[q.y & (RN - 1)], 1);
    }
    __syncthreads();
    if (threadIdx.x == 0) {
        int a = 0;
        for (int i = 0; i < RN; ++i) { offS[i] = a; a += cntS[i]; }
        offS[RN] = a;
    }
    __syncthreads();
    for (int i = threadIdx.x; i < RN; i += 256) cntS[i] = offS[i];
    __syncthreads();
    for (int i = threadIdx.x; i < ec; i += 256) {
        uint2 q = bucket[e0 + i];
        int p = atomicAdd(&cntS[q.y & (RN - 1)], 1);
        recS[p] = q;
    }
    __syncthreads();

    const float w = ew[lane];
    for (int r = wv; r < nn; r += 4) {
        const int s0 = offS[r], s1 = offS[r + 1];
        const float rl = RlA[(size_t)(n0 + r)*64 + lane];
        float acc = 0.f;
        int j = s0;
        for (; j + 8 <= s1; j += 8) {
            uint2 q0 = recS[j+0], q1 = recS[j+1], q2 = recS[j+2], q3 = recS[j+3];
            uint2 q4 = recS[j+4], q5 = recS[j+5], q6 = recS[j+6], q7 = recS[j+7];
            float l0 = bf2f(Lsb[(size_t)q0.x*64 + lane]);
            float l1 = bf2f(Lsb[(size_t)q1.x*64 + lane]);
            float l2 = bf2f(Lsb[(size_t)q2.x*64 + lane]);
            float l3 = bf2f(Lsb[(size_t)q3.x*64 + lane]);
            float l4 = bf2f(Lsb[(size_t)q4.x*64 + lane]);
            float l5 = bf2f(Lsb[(size_t)q5.x*64 + lane]);
            float l6 = bf2f(Lsb[(size_t)q6.x*64 + lane]);
            float l7 = bf2f(Lsb[(size_t)q7.x*64 + lane]);
            float f0 = __uint_as_float(q0.y & 0xFFFFFF80u);
            float f1 = __uint_as_float(q1.y & 0xFFFFFF80u);
            float f2 = __uint_as_float(q2.y & 0xFFFFFF80u);
            float f3 = __uint_as_float(q3.y & 0xFFFFFF80u);
            float f4 = __uint_as_float(q4.y & 0xFFFFFF80u);
            float f5 = __uint_as_float(q5.y & 0xFFFFFF80u);
            float f6 = __uint_as_float(q6.y & 0xFFFFFF80u);
            float f7 = __uint_as_float(q7.y & 0xFFFFFF80u);
            acc += fmaxf(fmaf(f0, w, rl + l0), 0.f);
            acc += fmaxf(fmaf(f1, w, rl + l1), 0.f);
            acc += fmaxf(fmaf(f2, w, rl + l2), 0.f);
            acc += fmaxf(fmaf(f3, w, rl + l3), 0.f);
            acc += fmaxf(fmaf(f4, w, rl + l4), 0.f);
            acc += fmaxf(fmaf(f5, w, rl + l5), 0.f);
            acc += fmaxf(fmaf(f6, w, rl + l6), 0.f);
            acc += fmaxf(fmaf(f7, w, rl + l7), 0.f);
        }
        for (; j < s1; ++j) {
            uint2 q = recS[j];
            float l = bf2f(Lsb[(size_t)q.x*64 + lane]);
            float f = __uint_as_float(q.y & 0xFFFFFF80u);
            acc += fmaxf(fmaf(f, w, rl + l), 0.f);
        }
        RlA[(size_t)(n0 + r)*64 + lane] = acc;
    }
}

// =============== fused cons update (cross-wave split-K, 32 rows/block) ===============
// u = relu(agg@Fc + c0@OW0B + deg*gc + ob0);  Ls_c = u@Hc + hc  (bf16)
// wave wv owns k-slice [wv*16, wv*16+16); partials accumulate via LDS f32 atomics.
__global__ __launch_bounds__(256) void consupd_kernel(
    const float* __restrict__ aggpre, const u16* __restrict__ c0,
    const int* __restrict__ deg,
    const float* __restrict__ Fc, const float* __restrict__ OW0B,
    const float* __restrict__ gc, const float* __restrict__ ob0,
    const float* __restrict__ Hc, const float* __restrict__ hc,
    u16* __restrict__ LsOut, int M)
{
    const int lane = threadIdx.x & 63;
    const int wv   = threadIdx.x >> 6;
    __shared__ __align__(16) float xs[32][64];    // agg rows, later stage-2 accumulator
    __shared__ __align__(16) float cs[32][64];    // c0 rows
    __shared__ __align__(16) float accS[32][64];  // stage-1 accumulator (u)
    const int rowTile = blockIdx.x * 32;
    const int k0 = wv * 16;

    const float g_l = gc[lane], b_l = ob0[lane];
#pragma unroll
    for (int i = 0; i < 8; ++i) {
        int r = wv*8 + i;
        int row = rowTile + r;
        int grow = (row < M) ? row : (M - 1);
        xs[r][lane]   = aggpre[(size_t)grow*64 + lane];
        cs[r][lane]   = bf2f(c0[(size_t)grow*64 + lane]);
        accS[r][lane] = fmaf((float)deg[grow], g_l, b_l);
    }
    __syncthreads();

    {   // stage 1 partials: k-slice of agg@Fc + c0@OW0B
        float wa[16], wb[16];
#pragma unroll
        for (int j = 0; j < 16; ++j) {
            wa[j] = Fc[(k0 + j)*64 + lane];
            wb[j] = OW0B[(k0 + j)*64 + lane];
        }
        for (int i = 0; i < 32; ++i) {
            int r = (wv*8 + i) & 31;   // stagger rows across waves
            float p = 0.f;
#pragma unroll
            for (int j4 = 0; j4 < 4; ++j4) {
                float4 x4 = *(const float4*)&xs[r][k0 + j4*4];
                float4 c4 = *(const float4*)&cs[r][k0 + j4*4];
                p = fmaf(x4.x, wa[j4*4+0], p); p = fmaf(c4.x, wb[j4*4+0], p);
                p = fmaf(x4.y, wa[j4*4+1], p); p = fmaf(c4.y, wb[j4*4+1], p);
                p = fmaf(x4.z, wa[j4*4+2], p); p = fmaf(c4.z, wb[j4*4+2], p);
                p = fmaf(x4.w, wa[j4*4+3], p); p = fmaf(c4.w, wb[j4*4+3], p);
            }
            atomicAdd(&accS[r][lane], p);
        }
    }
    __syncthreads();

    // re-init xs as stage-2 accumulator
    const float h_l = hc[lane];
#pragma unroll
    for (int i = 0; i < 8; ++i) xs[wv*8 + i][lane] = h_l;
    __syncthreads();

    {   // stage 2 partials: k-slice of relu(u) @ Hc
        float wh[16];
#pragma unroll
        for (int j = 0; j < 16; ++j) wh[j] = Hc[(k0 + j)*64 + lane];
        for (int i = 0; i < 32; ++i) {
            int r = (wv*8 + i) & 31;
            float p = 0.f;
#pragma unroll
            for (int j4 = 0; j4 < 4; ++j4) {
                float4 u4 = *(const float4*)&accS[r][k0 + j4*4];
                u4.x = fmaxf(u4.x, 0.f); u4.y = fmaxf(u4.y, 0.f);
                u4.z = fmaxf(u4.z, 0.f); u4.w = fmaxf(u4.w, 0.f);
                p = fmaf(u4.x, wh[j4*4+0], p);
                p = fmaf(u4.y, wh[j4*4+1], p);
                p = fmaf(u4.z, wh[j4*4+2], p);
                p = fmaf(u4.w, wh[j4*4+3], p);
            }
            atomicAdd(&xs[r][lane], p);
        }
    }
    __syncthreads();

#pragma unroll
    for (int i = 0; i < 8; ++i) {
        int r = wv*8 + i;
        int row = rowTile + r;
        if (row < M) LsOut[(size_t)row*64 + lane] = f2bf(xs[r][lane]);
    }
}

// =============== fused var update + heads (cross-wave split-K, 32 rows/block) ===============
__global__ __launch_bounds__(256) void varupdhead_kernel(
    const float* __restrict__ aggpre, const u16* __restrict__ v0,
    const int* __restrict__ deg,
    const float* __restrict__ Fv, const float* __restrict__ OW0B,
    const float* __restrict__ gv, const float* __restrict__ ob0,
    const float* __restrict__ Pw, const float* __restrict__ pbp, const float* __restrict__ pw1,
    const float* __restrict__ Vw, const float* __restrict__ vbp, const float* __restrict__ vw1,
    const float* __restrict__ vb1,
    float* __restrict__ out, int M)
{
    const int lane = threadIdx.x & 63;
    const int wv   = threadIdx.x >> 6;
    __shared__ __align__(16) float xs[32][64];    // agg rows
    __shared__ __align__(16) float cs[32][64];    // v0 rows
    __shared__ __align__(16) float accS[32][64];  // u
    __shared__ __align__(16) float tpS[32][64];   // policy-head partials
    __shared__ __align__(16) float tvS[32][64];   // value-head partials
    const int rowTile = blockIdx.x * 32;
    const int k0 = wv * 16;

    const float g_l = gv[lane], b_l = ob0[lane];
    const float pb_l = pbp[lane], vb_l = vbp[lane];
#pragma unroll
    for (int i = 0; i < 8; ++i) {
        int r = wv*8 + i;
        int row = rowTile + r;
        int grow = (row < M) ? row : (M - 1);
        xs[r][lane]   = aggpre[(size_t)grow*64 + lane];
        cs[r][lane]   = bf2f(v0[(size_t)grow*64 + lane]);
        accS[r][lane] = fmaf((float)deg[grow], g_l, b_l);
        tpS[r][lane]  = pb_l;
        tvS[r][lane]  = vb_l;
    }
    __syncthreads();

    {   // stage 1 partials
        float wa[16], wb[16];
#pragma unroll
        for (int j = 0; j < 16; ++j) {
            wa[j] = Fv[(k0 + j)*64 + lane];
            wb[j] = OW0B[(k0 + j)*64 + lane];
        }
        for (int i = 0; i < 32; ++i) {
            int r = (wv*8 + i) & 31;
            float p = 0.f;
#pragma unroll
            for (int j4 = 0; j4 < 4; ++j4) {
                float4 x4 = *(const float4*)&xs[r][k0 + j4*4];
                float4 c4 = *(const float4*)&cs[r][k0 + j4*4];
                p = fmaf(x4.x, wa[j4*4+0], p); p = fmaf(c4.x, wb[j4*4+0], p);
                p = fmaf(x4.y, wa[j4*4+1], p); p = fmaf(c4.y, wb[j4*4+1], p);
                p = fmaf(x4.z, wa[j4*4+2], p); p = fmaf(c4.z, wb[j4*4+2], p);
                p = fmaf(x4.w, wa[j4*4+3], p); p = fmaf(c4.w, wb[j4*4+3], p);
            }
            atomicAdd(&accS[r][lane], p);
        }
    }
    __syncthreads();

    {   // head partials: k-slice of relu(u)@Pw and relu(u)@Vw
        float wp[16], wq[16];
#pragma unroll
        for (int j = 0; j < 16; ++j) {
            wp[j] = Pw[(k0 + j)*64 + lane];
            wq[j] = Vw[(k0 + j)*64 + lane];
        }
        for (int i = 0; i < 32; ++i) {
            int r = (wv*8 + i) & 31;
            float tp = 0.f, tv = 0.f;
#pragma unroll
            for (int j4 = 0; j4 < 4; ++j4) {
                float4 u4 = *(const float4*)&accS[r][k0 + j4*4];
                u4.x = fmaxf(u4.x, 0.f); u4.y = fmaxf(u4.y, 0.f);
                u4.z = fmaxf(u4.z, 0.f); u4.w = fmaxf(u4.w, 0.f);
                tp = fmaf(u4.x, wp[j4*4+0], tp); tv = fmaf(u4.x, wq[j4*4+0], tv);
                tp = fmaf(u4.y, wp[j4*4+1], tp); tv = fmaf(u4.y, wq[j4*4+1], tv);
                tp = fmaf(u4.z, wp[j4*4+2], tp); tv = fmaf(u4.z, wq[j4*4+2], tv);
                tp = fmaf(u4.w, wp[j4*4+3], tp); tv = fmaf(u4.w, wq[j4*4+3], tv);
            }
            atomicAdd(&tpS[r][lane], tp);
            atomicAdd(&tvS[r][lane], tv);
        }
    }
    __syncthreads();

    const float p1w = pw1[lane], v1w = vw1[lane];
    const float vbias = vb1[0];
#pragma unroll
    for (int i = 0; i < 8; ++i) {
        int r = wv*8 + i;
        float a = fmaxf(tpS[r][lane], 0.f) * p1w;
        float b = fmaxf(tvS[r][lane], 0.f) * v1w;
#pragma unroll
        for (int m = 32; m >= 1; m >>= 1) {
            a += __shfl_xor(a, m, 64);
            b += __shfl_xor(b, m, 64);
        }
        int row = rowTile + r;
        if (lane == 0 && row < M) {
            out[row]     = b + vbias;   // value
            out[M + row] = a;           // policy
        }
    }
}

// =============== host launch ===============
#define AL256(x) (((x) + 255) & ~(size_t)255)

extern "C" void kernel_launch(void* const* d_in, const int* in_sizes, int n_in,
                              void* d_out, int out_size, void* d_ws, size_t ws_size,
                              hipStream_t stream)
{
    const float* cf  = (const float*)d_in[0];
    const int*   ei  = (const int*)  d_in[1];
    const float* ef  = (const float*)d_in[2];
    const float* vf  = (const float*)d_in[3];

    const float* cw0 = (const float*)d_in[4];
    const float* cb0 = (const float*)d_in[5];
    const float* cw1 = (const float*)d_in[6];
    const float* cb1 = (const float*)d_in[7];
    const float* vw0 = (const float*)d_in[8];
    const float* vb0 = (const float*)d_in[9];
    const float* vw1 = (const float*)d_in[10];
    const float* vb1 = (const float*)d_in[11];

    const float* vc_lw  = (const float*)d_in[12];
    const float* vc_lb  = (const float*)d_in[13];
    const float* vc_ew  = (const float*)d_in[14];
    const float* vc_rw  = (const float*)d_in[15];
    const float* vc_fw  = (const float*)d_in[16];
    const float* vc_fb  = (const float*)d_in[17];
    const float* vc_ow0 = (const float*)d_in[18];
    const float* vc_ob0 = (const float*)d_in[19];
    const float* vc_ow1 = (const float*)d_in[20];
    const float* vc_ob1 = (const float*)d_in[21];

    const float* cv_lw  = (const float*)d_in[22];
    const float* cv_lb  = (const float*)d_in[23];
    const float* cv_ew  = (const float*)d_in[24];
    const float* cv_rw  = (const float*)d_in[25];
    const float* cv_fw  = (const float*)d_in[26];
    const float* cv_fb  = (const float*)d_in[27];
    const float* cv_ow0 = (const float*)d_in[28];
    const float* cv_ob0 = (const float*)d_in[29];
    const float* cv_ow1 = (const float*)d_in[30];
    const float* cv_ob1 = (const float*)d_in[31];

    const float* pw0  = (const float*)d_in[32];
    const float* pb0  = (const float*)d_in[33];
    const float* pw1  = (const float*)d_in[34];
    const float* vhw0 = (const float*)d_in[35];
    const float* vhb0 = (const float*)d_in[36];
    const float* vhw1 = (const float*)d_in[37];
    const float* vhb1 = (const float*)d_in[38];

    const int NC = in_sizes[0] / 5;
    const int E  = in_sizes[1] / 2;
    const int NV = in_sizes[3] / 19;
    const int* eic = ei;
    const int* eiv = ei + E;

    const int nbC = (NC + RN - 1) >> RSH;
    const int nbV = (NV + RN - 1) >> RSH;

    // ---- workspace layout ----
    char* base = (char*)d_ws;
    size_t o = 0;
    float*  RlC = (float*)(base + o);  o += AL256((size_t)NC*64*4);
    u16*    c0b = (u16*)  (base + o);  o += AL256((size_t)NC*64*2);
    u16*    LsC = (u16*)  (base + o);  o += AL256((size_t)NC*64*2);
    float*  RlV = (float*)(base + o);  o += AL256((size_t)NV*64*4);
    u16*    v0b = (u16*)  (base + o);  o += AL256((size_t)NV*64*2);
    u16*    LsV = (u16*)  (base + o);  o += AL256((size_t)NV*64*2);
    uint2*  bktC = (uint2*)(base + o); o += AL256((size_t)E*8);
    uint2*  bktV = (uint2*)(base + o); o += AL256((size_t)E*8);
    int* cntC  = (int*)(base + o);  o += AL256((size_t)NC*4);
    int* cntV  = (int*)(base + o);  o += AL256((size_t)NV*4);
    int* cOffC = (int*)(base + o);  o += AL256(((size_t)nbC + 1)*4);
    int* curC  = (int*)(base + o);  o += AL256((size_t)nbC*4);
    int* cOffV = (int*)(base + o);  o += AL256(((size_t)nbV + 1)*4);
    int* curV  = (int*)(base + o);  o += AL256((size_t)nbV*4);
    float* Fc  = (float*)(base + o); o += AL256((size_t)4096*4);
    float* Hc  = (float*)(base + o); o += AL256((size_t)4096*4);
    float* Fv  = (float*)(base + o); o += AL256((size_t)4096*4);
    float* Pw  = (float*)(base + o); o += AL256((size_t)4096*4);
    float* Vw  = (float*)(base + o); o += AL256((size_t)4096*4);
    float* gc  = (float*)(base + o); o += AL256((size_t)64*4);
    float* hc  = (float*)(base + o); o += AL256((size_t)64*4);
    float* gv  = (float*)(base + o); o += AL256((size_t)64*4);
    float* pbp = (float*)(base + o); o += AL256((size_t)64*4);
    float* vbp = (float*)(base + o); o += AL256((size_t)64*4);

    if (o > ws_size) return;                    // insufficient scratch: fail visibly
    if (nbC + nbV > NBINS_MAX) return;          // binning LDS would overflow

    dim3 blk(256);
    dim3 gRowsC((unsigned)((NC + 31) / 32));
    dim3 gRowsV((unsigned)((NV + 31) / 32));
    dim3 gE((unsigned)((E + 255) / 256));

    // ---- degree histogram + coarse offsets ----
    (void)hipMemsetAsync(cntC, 0, (size_t)NC*4, stream);
    (void)hipMemsetAsync(cntV, 0, (size_t)NV*4, stream);
    hist2_kernel<<<gE, blk, 0, stream>>>(eic, eiv, cntC, cntV, E);
    coarse_kernel<<<dim3(1), blk, 0, stream>>>(cntC, NC, nbC, cOffC, curC);
    coarse_kernel<<<dim3(1), blk, 0, stream>>>(cntV, NV, nbV, cOffV, curV);

    // ---- collapsed weights ----
    prep_kernel<<<dim3(1), blk, 0, stream>>>(
        vc_fw, vc_fb, vc_ow0, vc_ow1, vc_ob1,
        cv_rw, cv_fw, cv_fb, cv_ow0, cv_ow1, cv_ob1,
        pw0, pb0, vhw0, vhb0,
        Fc, gc, Hc, hc, Fv, gv, Pw, pbp, Vw, vbp);

    // ---- embeddings (+ fused per-node linears) ----
    embc_kernel<<<gRowsC, blk, 0, stream>>>(cf, cw0, cb0, cw1, cb1,
                                            vc_lw, vc_lb, c0b, RlC, NC);
    embv_kernel<<<gRowsV, blk, 0, stream>>>(vf, vw0, vb0, vw1, vb1,
                                            vc_rw, cv_lw, cv_lb, v0b, LsV, RlV, NV);

    // ---- block-local binned scatter (one pass over edge stream) ----
    binscatter_kernel<<<dim3(128), blk, 0, stream>>>(eic, eiv, ef, curC, curV,
                                                     bktC, bktV, nbC, nbV, E);

    // ---- conv1: v -> c ----
    aggsort_kernel<<<dim3((unsigned)nbC), blk, 0, stream>>>(cOffC, bktC, RlC, LsV, vc_ew, NC);
    consupd_kernel<<<gRowsC, blk, 0, stream>>>(RlC, c0b, cntC,
                                               Fc, vc_ow0 + 64*64, gc, vc_ob0,
                                               Hc, hc, LsC, NC);

    // ---- conv2: c -> v ----
    aggsort_kernel<<<dim3((unsigned)nbV), blk, 0, stream>>>(cOffV, bktV, RlV, LsC, cv_ew, NV);
    varupdhead_kernel<<<gRowsV, blk, 0, stream>>>(RlV, v0b, cntV,
                                                  Fv, cv_ow0 + 64*64, gv, cv_ob0,
                                                  Pw, pbp, pw1, Vw, vbp, vhw1, vhb1,
                                                  (float*)d_out, NV);
}

// Round 13
// 1171.586 us; speedup vs baseline: 1.7983x; 1.7983x over previous
//
#include <hip/hip_runtime.h>

typedef unsigned short u16;

#define RN  128   // nodes per coarse bucket
#define RSH 7
#define CAP 6400  // max records per coarse bucket staged in LDS (mean ~2560)
#define NBINS_MAX 4096

__device__ __forceinline__ float bf2f(u16 u) {
    return __uint_as_float(((unsigned int)u) << 16);
}
__device__ __forceinline__ u16 f2bf(float f) {
    unsigned int x = __float_as_uint(f);
    return (u16)((x + 0x7fffu + ((x >> 16) & 1u)) >> 16);
}

// =============== on-device weight prep (algebraic collapse) ===============
__device__ __forceinline__ void mm64(const float* A, const float* B, float* C, int lane)
{
    float bcol[64];
#pragma unroll
    for (int m = 0; m < 64; ++m) bcol[m] = B[m*64 + lane];
    for (int k = 0; k < 64; ++k) {
        float acc = 0.f;
#pragma unroll
        for (int m = 0; m < 64; ++m) acc = fmaf(A[k*64 + m], bcol[m], acc);
        C[k*64 + lane] = acc;
    }
}

__device__ __forceinline__ void vm64(const float* a, const float* B, const float* add,
                                     float* c, int lane)
{
    float acc = (add != 0) ? add[lane] : 0.f;
#pragma unroll
    for (int m = 0; m < 64; ++m) acc = fmaf(a[m], B[m*64 + lane], acc);
    c[lane] = acc;
}

__global__ __launch_bounds__(256) void prep_kernel(
    const float* vc_fw, const float* vc_fb, const float* vc_ow0,
    const float* vc_ow1, const float* vc_ob1,
    const float* cv_rw, const float* cv_fw, const float* cv_fb,
    const float* cv_ow0, const float* cv_ow1, const float* cv_ob1,
    const float* pw0, const float* pb0, const float* vhw0, const float* vhb0,
    float* Fc, float* gc, float* Hc, float* hc, float* Fv, float* gv,
    float* Pw, float* pbp, float* Vw, float* vbp)
{
    const int wv = threadIdx.x >> 6;
    const int lane = threadIdx.x & 63;
    if (wv == 0) {
        mm64(vc_fw, vc_ow0, Fc, lane);
        vm64(vc_fb, vc_ow0, 0, gc, lane);
    } else if (wv == 1) {
        mm64(vc_ow1, cv_rw, Hc, lane);
        vm64(vc_ob1, cv_rw, 0, hc, lane);
    } else if (wv == 2) {
        mm64(cv_fw, cv_ow0, Fv, lane);
        vm64(cv_fb, cv_ow0, 0, gv, lane);
    } else {
        mm64(cv_ow1, pw0, Pw, lane);
        vm64(cv_ob1, pw0, pb0, pbp, lane);
        mm64(cv_ow1, vhw0, Vw, lane);
        vm64(cv_ob1, vhw0, vhb0, vbp, lane);
    }
}

// =============== embeddings (fused with downstream per-node linears) ===============
__global__ __launch_bounds__(256) void embc_kernel(
    const float* __restrict__ X,
    const float* __restrict__ W0, const float* __restrict__ B0,
    const float* __restrict__ W1, const float* __restrict__ B1,
    const float* __restrict__ LW, const float* __restrict__ LB,
    u16* __restrict__ c0out, float* __restrict__ RlOut, int M)
{
    const int lane = threadIdx.x & 63;
    const int wv   = threadIdx.x >> 6;
    __shared__ __align__(16) float xs[4][8*5];
    __shared__ __align__(16) float hb[4][8][64];
    __shared__ __align__(16) float yb[4][8][64];
    const int rowTile = (blockIdx.x*4 + wv)*8;

    for (int idx = lane; idx < 8*5; idx += 64) {
        long gi = (long)rowTile*5 + idx;
        xs[wv][idx] = (gi < (long)M*5) ? X[gi] : 0.f;
    }
    {
        float w0[5];
#pragma unroll
        for (int k = 0; k < 5; ++k) w0[k] = W0[k*64 + lane];
        const float b0 = B0[lane];
#pragma unroll
        for (int r = 0; r < 8; ++r) {
            float acc = b0;
#pragma unroll
            for (int k = 0; k < 5; ++k) acc = fmaf(xs[wv][r*5 + k], w0[k], acc);
            hb[wv][r][lane] = fmaxf(acc, 0.f);
        }
    }
    {
        float w1[64];
#pragma unroll
        for (int k = 0; k < 64; ++k) w1[k] = W1[k*64 + lane];
        const float b1 = B1[lane];
#pragma unroll
        for (int r = 0; r < 8; ++r) {
            float acc = b1;
#pragma unroll
            for (int k4 = 0; k4 < 16; ++k4) {
                float4 h4 = *(const float4*)&hb[wv][r][k4*4];
                acc = fmaf(h4.x, w1[k4*4+0], acc);
                acc = fmaf(h4.y, w1[k4*4+1], acc);
                acc = fmaf(h4.z, w1[k4*4+2], acc);
                acc = fmaf(h4.w, w1[k4*4+3], acc);
            }
            float y = fmaxf(acc, 0.f);
            yb[wv][r][lane] = y;
            int row = rowTile + r;
            if (row < M) c0out[(size_t)row*64 + lane] = f2bf(y);
        }
    }
    {
        float w[64];
#pragma unroll
        for (int k = 0; k < 64; ++k) w[k] = LW[k*64 + lane];
        const float bb = LB[lane];
#pragma unroll
        for (int r = 0; r < 8; ++r) {
            float acc = bb;
#pragma unroll
            for (int k4 = 0; k4 < 16; ++k4) {
                float4 y4 = *(const float4*)&yb[wv][r][k4*4];
                acc = fmaf(y4.x, w[k4*4+0], acc);
                acc = fmaf(y4.y, w[k4*4+1], acc);
                acc = fmaf(y4.z, w[k4*4+2], acc);
                acc = fmaf(y4.w, w[k4*4+3], acc);
            }
            int row = rowTile + r;
            if (row < M) RlOut[(size_t)row*64 + lane] = acc;
        }
    }
}

__global__ __launch_bounds__(256) void embv_kernel(
    const float* __restrict__ X,
    const float* __restrict__ W0, const float* __restrict__ B0,
    const float* __restrict__ W1, const float* __restrict__ B1,
    const float* __restrict__ RW,
    const float* __restrict__ LW, const float* __restrict__ LB,
    u16* __restrict__ v0out, u16* __restrict__ LsOut,
    float* __restrict__ RlOut, int M)
{
    const int lane = threadIdx.x & 63;
    const int wv   = threadIdx.x >> 6;
    __shared__ __align__(16) float xs[4][8*19];
    __shared__ __align__(16) float hb[4][8][64];
    __shared__ __align__(16) float yb[4][8][64];
    const int rowTile = (blockIdx.x*4 + wv)*8;

    for (int idx = lane; idx < 8*19; idx += 64) {
        long gi = (long)rowTile*19 + idx;
        xs[wv][idx] = (gi < (long)M*19) ? X[gi] : 0.f;
    }
    {
        float w0[19];
#pragma unroll
        for (int k = 0; k < 19; ++k) w0[k] = W0[k*64 + lane];
        const float b0 = B0[lane];
#pragma unroll
        for (int r = 0; r < 8; ++r) {
            float acc = b0;
#pragma unroll
            for (int k = 0; k < 19; ++k) acc = fmaf(xs[wv][r*19 + k], w0[k], acc);
            hb[wv][r][lane] = fmaxf(acc, 0.f);
        }
    }
    {
        float w1[64];
#pragma unroll
        for (int k = 0; k < 64; ++k) w1[k] = W1[k*64 + lane];
        const float b1 = B1[lane];
#pragma unroll
        for (int r = 0; r < 8; ++r) {
            float acc = b1;
#pragma unroll
            for (int k4 = 0; k4 < 16; ++k4) {
                float4 h4 = *(const float4*)&hb[wv][r][k4*4];
                acc = fmaf(h4.x, w1[k4*4+0], acc);
                acc = fmaf(h4.y, w1[k4*4+1], acc);
                acc = fmaf(h4.z, w1[k4*4+2], acc);
                acc = fmaf(h4.w, w1[k4*4+3], acc);
            }
            float y = fmaxf(acc, 0.f);
            yb[wv][r][lane] = y;
            int row = rowTile + r;
            if (row < M) v0out[(size_t)row*64 + lane] = f2bf(y);
        }
    }
    {
        float w[64];
#pragma unroll
        for (int k = 0; k < 64; ++k) w[k] = RW[k*64 + lane];
#pragma unroll
        for (int r = 0; r < 8; ++r) {
            float acc = 0.f;
#pragma unroll
            for (int k4 = 0; k4 < 16; ++k4) {
                float4 y4 = *(const float4*)&yb[wv][r][k4*4];
                acc = fmaf(y4.x, w[k4*4+0], acc);
                acc = fmaf(y4.y, w[k4*4+1], acc);
                acc = fmaf(y4.z, w[k4*4+2], acc);
                acc = fmaf(y4.w, w[k4*4+3], acc);
            }
            int row = rowTile + r;
            if (row < M) LsOut[(size_t)row*64 + lane] = f2bf(acc);
        }
    }
    {
        float w[64];
#pragma unroll
        for (int k = 0; k < 64; ++k) w[k] = LW[k*64 + lane];
        const float bb = LB[lane];
#pragma unroll
        for (int r = 0; r < 8; ++r) {
            float acc = bb;
#pragma unroll
            for (int k4 = 0; k4 < 16; ++k4) {
                float4 y4 = *(const float4*)&yb[wv][r][k4*4];
                acc = fmaf(y4.x, w[k4*4+0], acc);
                acc = fmaf(y4.y, w[k4*4+1], acc);
                acc = fmaf(y4.z, w[k4*4+2], acc);
                acc = fmaf(y4.w, w[k4*4+3], acc);
            }
            int row = rowTile + r;
            if (row < M) RlOut[(size_t)row*64 + lane] = acc;
        }
    }
}

// =============== per-node degree histogram ===============
__global__ __launch_bounds__(256) void hist2_kernel(
    const int* __restrict__ eic, const int* __restrict__ eiv,
    int* cntC, int* cntV, int E)
{
    int e = blockIdx.x*256 + threadIdx.x;
    if (e >= E) return;
    atomicAdd(&cntC[eic[e]], 1);
    atomicAdd(&cntV[eiv[e]], 1);
}

// =============== coarse-bucket offsets (one block per direction) ===============
__global__ __launch_bounds__(256) void coarse_kernel(
    const int* __restrict__ cnt, int N, int nb, int* cOff, int* cur)
{
    __shared__ int cs[2049];
    for (int i = threadIdx.x; i < nb; i += 256) {
        int s = 0;
        int basei = i << RSH;
        int lim = N - basei; if (lim > RN) lim = RN;
        for (int j = 0; j < lim; ++j) s += cnt[basei + j];
        cs[i] = s;
    }
    __syncthreads();
    if (threadIdx.x == 0) {
        int a = 0;
        for (int i = 0; i < nb; ++i) { int t = cs[i]; cs[i] = a; a += t; }
        cs[nb] = a;
    }
    __syncthreads();
    for (int i = threadIdx.x; i < nb; i += 256) { cOff[i] = cs[i]; cur[i] = cs[i]; }
    if (threadIdx.x == 0) cOff[nb] = cs[nb];
}

// =============== block-local two-pass binned scatter ===============
__global__ __launch_bounds__(256) void binscatter_kernel(
    const int* __restrict__ eic, const int* __restrict__ eiv,
    const float* __restrict__ ef,
    int* curC, int* curV,
    uint2* __restrict__ bC, uint2* __restrict__ bV,
    int nbC, int nbV, int E)
{
    __shared__ int bins[NBINS_MAX];
    const int nb = nbC + nbV;
    const int chunk = (E + (int)gridDim.x - 1) / (int)gridDim.x;
    const int e0 = blockIdx.x * chunk;
    int e1 = e0 + chunk; if (e1 > E) e1 = E;

    for (int i = threadIdx.x; i < nb; i += 256) bins[i] = 0;
    __syncthreads();

    for (int e = e0 + threadIdx.x; e < e1; e += 256) {
        atomicAdd(&bins[eic[e] >> RSH], 1);
        atomicAdd(&bins[nbC + (eiv[e] >> RSH)], 1);
    }
    __syncthreads();

    for (int i = threadIdx.x; i < nbC; i += 256) {
        int c = bins[i];
        bins[i] = (c > 0) ? atomicAdd(&curC[i], c) : 0;
    }
    for (int i = threadIdx.x; i < nbV; i += 256) {
        int c = bins[nbC + i];
        bins[nbC + i] = (c > 0) ? atomicAdd(&curV[i], c) : 0;
    }
    __syncthreads();

    for (int e = e0 + threadIdx.x; e < e1; e += 256) {
        const int c = eic[e], v = eiv[e];
        const unsigned fb = __float_as_uint(ef[e]) & 0xFFFFFF80u;
        int pc = atomicAdd(&bins[c >> RSH], 1);
        bC[pc] = make_uint2((unsigned)v, fb | (unsigned)(c & (RN - 1)));
        int pv = atomicAdd(&bins[nbC + (v >> RSH)], 1);
        bV[pv] = make_uint2((unsigned)c, fb | (unsigned)(v & (RN - 1)));
    }
}

// =============== fused in-LDS counting sort + per-node aggregation ===============
__global__ __launch_bounds__(256) void aggsort_kernel(
    const int* __restrict__ cOff, const uint2* __restrict__ bucket,
    float* RlA, const u16* __restrict__ Lsb,
    const float* __restrict__ ew, int N)
{
    const int b = blockIdx.x;
    const int lane = threadIdx.x & 63;
    const int wv   = threadIdx.x >> 6;
    const int n0 = b << RSH;
    int nn = N - n0; if (nn > RN) nn = RN;

    __shared__ uint2 recS[CAP];
    __shared__ int cntS[RN];
    __shared__ int offS[RN + 1];

    const int e0 = cOff[b];
    int ec = cOff[b + 1] - e0;
    if (ec > CAP) ec = CAP;

    for (int i = threadIdx.x; i < RN; i += 256) cntS[i] = 0;
    __syncthreads();
    for (int i = threadIdx.x; i < ec; i += 256) {
        uint2 q = bucket[e0 + i];
        atomicAdd(&cntS[q.y & (RN - 1)], 1);
    }
    __syncthreads();
    if (threadIdx.x == 0) {
        int a = 0;
        for (int i = 0; i < RN; ++i) { offS[i] = a; a += cntS[i]; }
        offS[RN] = a;
    }
    __syncthreads();
    for (int i = threadIdx.x; i < RN; i += 256) cntS[i] = offS[i];
    __syncthreads();
    for (int i = threadIdx.x; i < ec; i += 256) {
        uint2 q = bucket[e0 + i];
        int p = atomicAdd(&cntS[q.y & (RN - 1)], 1);
        recS[p] = q;
    }
    __syncthreads();

    const float w = ew[lane];
    for (int r = wv; r < nn; r += 4) {
        const int s0 = offS[r], s1 = offS[r + 1];
        const float rl = RlA[(size_t)(n0 + r)*64 + lane];
        float acc = 0.f;
        int j = s0;
        for (; j + 8 <= s1; j += 8) {
            uint2 q0 = recS[j+0], q1 = recS[j+1], q2 = recS[j+2], q3 = recS[j+3];
            uint2 q4 = recS[j+4], q5 = recS[j+5], q6 = recS[j+6], q7 = recS[j+7];
            float l0 = bf2f(Lsb[(size_t)q0.x*64 + lane]);
            float l1 = bf2f(Lsb[(size_t)q1.x*64 + lane]);
            float l2 = bf2f(Lsb[(size_t)q2.x*64 + lane]);
            float l3 = bf2f(Lsb[(size_t)q3.x*64 + lane]);
            float l4 = bf2f(Lsb[(size_t)q4.x*64 + lane]);
            float l5 = bf2f(Lsb[(size_t)q5.x*64 + lane]);
            float l6 = bf2f(Lsb[(size_t)q6.x*64 + lane]);
            float l7 = bf2f(Lsb[(size_t)q7.x*64 + lane]);
            float f0 = __uint_as_float(q0.y & 0xFFFFFF80u);
            float f1 = __uint_as_float(q1.y & 0xFFFFFF80u);
            float f2 = __uint_as_float(q2.y & 0xFFFFFF80u);
            float f3 = __uint_as_float(q3.y & 0xFFFFFF80u);
            float f4 = __uint_as_float(q4.y & 0xFFFFFF80u);
            float f5 = __uint_as_float(q5.y & 0xFFFFFF80u);
            float f6 = __uint_as_float(q6.y & 0xFFFFFF80u);
            float f7 = __uint_as_float(q7.y & 0xFFFFFF80u);
            acc += fmaxf(fmaf(f0, w, rl + l0), 0.f);
            acc += fmaxf(fmaf(f1, w, rl + l1), 0.f);
            acc += fmaxf(fmaf(f2, w, rl + l2), 0.f);
            acc += fmaxf(fmaf(f3, w, rl + l3), 0.f);
            acc += fmaxf(fmaf(f4, w, rl + l4), 0.f);
            acc += fmaxf(fmaf(f5, w, rl + l5), 0.f);
            acc += fmaxf(fmaf(f6, w, rl + l6), 0.f);
            acc += fmaxf(fmaf(f7, w, rl + l7), 0.f);
        }
        for (; j < s1; ++j) {
            uint2 q = recS[j];
            float l = bf2f(Lsb[(size_t)q.x*64 + lane]);
            float f = __uint_as_float(q.y & 0xFFFFFF80u);
            acc += fmaxf(fmaf(f, w, rl + l), 0.f);
        }
        RlA[(size_t)(n0 + r)*64 + lane] = acc;
    }
}

// =============== fused cons update (wave-parallel matrix split, 32 rows/block) ===============
// u = relu(agg@Fc + c0@OW0B + deg*gc + ob0);  Ls_c = u@Hc + hc  (bf16)
// Stage 1: waves 0-1 apply Fc to agg rows [0,16)/[16,32); waves 2-3 apply OW0B to c0 rows.
// Each wave holds ONE 64-VGPR weight column; partials go to privately-owned LDS (no atomics).
__global__ __launch_bounds__(256) void consupd_kernel(
    const float* __restrict__ aggpre, const u16* __restrict__ c0,
    const int* __restrict__ deg,
    const float* __restrict__ Fc, const float* __restrict__ OW0B,
    const float* __restrict__ gc, const float* __restrict__ ob0,
    const float* __restrict__ Hc, const float* __restrict__ hc,
    u16* __restrict__ LsOut, int M)
{
    const int lane = threadIdx.x & 63;
    const int wv   = threadIdx.x >> 6;
    __shared__ __align__(16) float xs[32][64];   // agg rows, later u
    __shared__ __align__(16) float cs[32][64];   // c0 rows
    __shared__ __align__(16) float pA[32][64];   // F-partial (pre-init with deg*gc+ob0)
    __shared__ __align__(16) float pB[32][64];   // OW0B-partial
    const int rowTile = blockIdx.x * 32;

    const float g_l = gc[lane], b_l = ob0[lane];
#pragma unroll
    for (int i = 0; i < 8; ++i) {
        int r = wv*8 + i;
        int row = rowTile + r;
        int grow = (row < M) ? row : (M - 1);
        xs[r][lane] = aggpre[(size_t)grow*64 + lane];
        cs[r][lane] = bf2f(c0[(size_t)grow*64 + lane]);
        pA[r][lane] = fmaf((float)deg[grow], g_l, b_l);
    }
    __syncthreads();

    {   // stage 1: one weight matrix per wave
        const bool isB = (wv >= 2);
        const float* W = isB ? OW0B : Fc;
        float w[64];
#pragma unroll
        for (int k = 0; k < 64; ++k) w[k] = W[k*64 + lane];
        const int r0 = (wv & 1) * 16;
        for (int i = 0; i < 16; ++i) {
            int r = r0 + i;
            float p = 0.f;
#pragma unroll
            for (int k4 = 0; k4 < 16; ++k4) {
                float4 s4 = isB ? *(const float4*)&cs[r][k4*4]
                                : *(const float4*)&xs[r][k4*4];
                p = fmaf(s4.x, w[k4*4+0], p);
                p = fmaf(s4.y, w[k4*4+1], p);
                p = fmaf(s4.z, w[k4*4+2], p);
                p = fmaf(s4.w, w[k4*4+3], p);
            }
            if (isB) pB[r][lane] = p;
            else     pA[r][lane] += p;
        }
    }
    __syncthreads();

    // u = relu(pA + pB) -> xs
#pragma unroll
    for (int i = 0; i < 8; ++i) {
        int r = wv*8 + i;
        xs[r][lane] = fmaxf(pA[r][lane] + pB[r][lane], 0.f);
    }
    __syncthreads();

    {   // stage 2: u @ Hc + hc (all 4 waves, 8 rows each)
        float w[64];
#pragma unroll
        for (int k = 0; k < 64; ++k) w[k] = Hc[k*64 + lane];
        const float h_l = hc[lane];
#pragma unroll
        for (int i = 0; i < 8; ++i) {
            int r = wv*8 + i;
            float acc = h_l;
#pragma unroll
            for (int k4 = 0; k4 < 16; ++k4) {
                float4 u4 = *(const float4*)&xs[r][k4*4];
                acc = fmaf(u4.x, w[k4*4+0], acc);
                acc = fmaf(u4.y, w[k4*4+1], acc);
                acc = fmaf(u4.z, w[k4*4+2], acc);
                acc = fmaf(u4.w, w[k4*4+3], acc);
            }
            int row = rowTile + r;
            if (row < M) LsOut[(size_t)row*64 + lane] = f2bf(acc);
        }
    }
}

// =============== fused var update + heads (wave-parallel matrix split, 32 rows/block) ===============
// Stage 1 as consupd; heads: waves 0-1 policy rows [0,16)/[16,32), waves 2-3 value.
__global__ __launch_bounds__(256) void varupdhead_kernel(
    const float* __restrict__ aggpre, const u16* __restrict__ v0,
    const int* __restrict__ deg,
    const float* __restrict__ Fv, const float* __restrict__ OW0B,
    const float* __restrict__ gv, const float* __restrict__ ob0,
    const float* __restrict__ Pw, const float* __restrict__ pbp, const float* __restrict__ pw1,
    const float* __restrict__ Vw, const float* __restrict__ vbp, const float* __restrict__ vw1,
    const float* __restrict__ vb1,
    float* __restrict__ out, int M)
{
    const int lane = threadIdx.x & 63;
    const int wv   = threadIdx.x >> 6;
    __shared__ __align__(16) float xs[32][64];   // agg rows, later u
    __shared__ __align__(16) float cs[32][64];   // v0 rows
    __shared__ __align__(16) float pA[32][64];
    __shared__ __align__(16) float pB[32][64];
    const int rowTile = blockIdx.x * 32;

    const float g_l = gv[lane], b_l = ob0[lane];
#pragma unroll
    for (int i = 0; i < 8; ++i) {
        int r = wv*8 + i;
        int row = rowTile + r;
        int grow = (row < M) ? row : (M - 1);
        xs[r][lane] = aggpre[(size_t)grow*64 + lane];
        cs[r][lane] = bf2f(v0[(size_t)grow*64 + lane]);
        pA[r][lane] = fmaf((float)deg[grow], g_l, b_l);
    }
    __syncthreads();

    {   // stage 1: one weight matrix per wave
        const bool isB = (wv >= 2);
        const float* W = isB ? OW0B : Fv;
        float w[64];
#pragma unroll
        for (int k = 0; k < 64; ++k) w[k] = W[k*64 + lane];
        const int r0 = (wv & 1) * 16;
        for (int i = 0; i < 16; ++i) {
            int r = r0 + i;
            float p = 0.f;
#pragma unroll
            for (int k4 = 0; k4 < 16; ++k4) {
                float4 s4 = isB ? *(const float4*)&cs[r][k4*4]
                                : *(const float4*)&xs[r][k4*4];
                p = fmaf(s4.x, w[k4*4+0], p);
                p = fmaf(s4.y, w[k4*4+1], p);
                p = fmaf(s4.z, w[k4*4+2], p);
                p = fmaf(s4.w, w[k4*4+3], p);
            }
            if (isB) pB[r][lane] = p;
            else     pA[r][lane] += p;
        }
    }
    __syncthreads();

    // u = relu(pA + pB) -> xs
#pragma unroll
    for (int i = 0; i < 8; ++i) {
        int r = wv*8 + i;
        xs[r][lane] = fmaxf(pA[r][lane] + pB[r][lane], 0.f);
    }
    __syncthreads();

    {   // heads: one head matrix per wave
        const bool isV = (wv >= 2);
        const float* W = isV ? Vw : Pw;
        const float bias_l = isV ? vbp[lane] : pbp[lane];
        const float mul_l  = isV ? vw1[lane] : pw1[lane];
        const float vbias  = vb1[0];
        float w[64];
#pragma unroll
        for (int k = 0; k < 64; ++k) w[k] = W[k*64 + lane];
        const int r0 = (wv & 1) * 16;
        for (int i = 0; i < 16; ++i) {
            int r = r0 + i;
            float t = bias_l;
#pragma unroll
            for (int k4 = 0; k4 < 16; ++k4) {
                float4 u4 = *(const float4*)&xs[r][k4*4];
                t = fmaf(u4.x, w[k4*4+0], t);
                t = fmaf(u4.y, w[k4*4+1], t);
                t = fmaf(u4.z, w[k4*4+2], t);
                t = fmaf(u4.w, w[k4*4+3], t);
            }
            t = fmaxf(t, 0.f) * mul_l;
#pragma unroll
            for (int m = 32; m >= 1; m >>= 1) t += __shfl_xor(t, m, 64);
            int row = rowTile + r;
            if (lane == 0 && row < M) {
                if (isV) out[row]     = t + vbias;  // value
                else     out[M + row] = t;          // policy
            }
        }
    }
}

// =============== host launch ===============
#define AL256(x) (((x) + 255) & ~(size_t)255)

extern "C" void kernel_launch(void* const* d_in, const int* in_sizes, int n_in,
                              void* d_out, int out_size, void* d_ws, size_t ws_size,
                              hipStream_t stream)
{
    const float* cf  = (const float*)d_in[0];
    const int*   ei  = (const int*)  d_in[1];
    const float* ef  = (const float*)d_in[2];
    const float* vf  = (const float*)d_in[3];

    const float* cw0 = (const float*)d_in[4];
    const float* cb0 = (const float*)d_in[5];
    const float* cw1 = (const float*)d_in[6];
    const float* cb1 = (const float*)d_in[7];
    const float* vw0 = (const float*)d_in[8];
    const float* vb0 = (const float*)d_in[9];
    const float* vw1 = (const float*)d_in[10];
    const float* vb1 = (const float*)d_in[11];

    const float* vc_lw  = (const float*)d_in[12];
    const float* vc_lb  = (const float*)d_in[13];
    const float* vc_ew  = (const float*)d_in[14];
    const float* vc_rw  = (const float*)d_in[15];
    const float* vc_fw  = (const float*)d_in[16];
    const float* vc_fb  = (const float*)d_in[17];
    const float* vc_ow0 = (const float*)d_in[18];
    const float* vc_ob0 = (const float*)d_in[19];
    const float* vc_ow1 = (const float*)d_in[20];
    const float* vc_ob1 = (const float*)d_in[21];

    const float* cv_lw  = (const float*)d_in[22];
    const float* cv_lb  = (const float*)d_in[23];
    const float* cv_ew  = (const float*)d_in[24];
    const float* cv_rw  = (const float*)d_in[25];
    const float* cv_fw  = (const float*)d_in[26];
    const float* cv_fb  = (const float*)d_in[27];
    const float* cv_ow0 = (const float*)d_in[28];
    const float* cv_ob0 = (const float*)d_in[29];
    const float* cv_ow1 = (const float*)d_in[30];
    const float* cv_ob1 = (const float*)d_in[31];

    const float* pw0  = (const float*)d_in[32];
    const float* pb0  = (const float*)d_in[33];
    const float* pw1  = (const float*)d_in[34];
    const float* vhw0 = (const float*)d_in[35];
    const float* vhb0 = (const float*)d_in[36];
    const float* vhw1 = (const float*)d_in[37];
    const float* vhb1 = (const float*)d_in[38];

    const int NC = in_sizes[0] / 5;
    const int E  = in_sizes[1] / 2;
    const int NV = in_sizes[3] / 19;
    const int* eic = ei;
    const int* eiv = ei + E;

    const int nbC = (NC + RN - 1) >> RSH;
    const int nbV = (NV + RN - 1) >> RSH;

    // ---- workspace layout ----
    char* base = (char*)d_ws;
    size_t o = 0;
    float*  RlC = (float*)(base + o);  o += AL256((size_t)NC*64*4);
    u16*    c0b = (u16*)  (base + o);  o += AL256((size_t)NC*64*2);
    u16*    LsC = (u16*)  (base + o);  o += AL256((size_t)NC*64*2);
    float*  RlV = (float*)(base + o);  o += AL256((size_t)NV*64*4);
    u16*    v0b = (u16*)  (base + o);  o += AL256((size_t)NV*64*2);
    u16*    LsV = (u16*)  (base + o);  o += AL256((size_t)NV*64*2);
    uint2*  bktC = (uint2*)(base + o); o += AL256((size_t)E*8);
    uint2*  bktV = (uint2*)(base + o); o += AL256((size_t)E*8);
    int* cntC  = (int*)(base + o);  o += AL256((size_t)NC*4);
    int* cntV  = (int*)(base + o);  o += AL256((size_t)NV*4);
    int* cOffC = (int*)(base + o);  o += AL256(((size_t)nbC + 1)*4);
    int* curC  = (int*)(base + o);  o += AL256((size_t)nbC*4);
    int* cOffV = (int*)(base + o);  o += AL256(((size_t)nbV + 1)*4);
    int* curV  = (int*)(base + o);  o += AL256((size_t)nbV*4);
    float* Fc  = (float*)(base + o); o += AL256((size_t)4096*4);
    float* Hc  = (float*)(base + o); o += AL256((size_t)4096*4);
    float* Fv  = (float*)(base + o); o += AL256((size_t)4096*4);
    float* Pw  = (float*)(base + o); o += AL256((size_t)4096*4);
    float* Vw  = (float*)(base + o); o += AL256((size_t)4096*4);
    float* gc  = (float*)(base + o); o += AL256((size_t)64*4);
    float* hc  = (float*)(base + o); o += AL256((size_t)64*4);
    float* gv  = (float*)(base + o); o += AL256((size_t)64*4);
    float* pbp = (float*)(base + o); o += AL256((size_t)64*4);
    float* vbp = (float*)(base + o); o += AL256((size_t)64*4);

    if (o > ws_size) return;                    // insufficient scratch: fail visibly
    if (nbC + nbV > NBINS_MAX) return;          // binning LDS would overflow

    dim3 blk(256);
    dim3 gRowsC((unsigned)((NC + 31) / 32));
    dim3 gRowsV((unsigned)((NV + 31) / 32));
    dim3 gE((unsigned)((E + 255) / 256));

    // ---- degree histogram + coarse offsets ----
    (void)hipMemsetAsync(cntC, 0, (size_t)NC*4, stream);
    (void)hipMemsetAsync(cntV, 0, (size_t)NV*4, stream);
    hist2_kernel<<<gE, blk, 0, stream>>>(eic, eiv, cntC, cntV, E);
    coarse_kernel<<<dim3(1), blk, 0, stream>>>(cntC, NC, nbC, cOffC, curC);
    coarse_kernel<<<dim3(1), blk, 0, stream>>>(cntV, NV, nbV, cOffV, curV);

    // ---- collapsed weights ----
    prep_kernel<<<dim3(1), blk, 0, stream>>>(
        vc_fw, vc_fb, vc_ow0, vc_ow1, vc_ob1,
        cv_rw, cv_fw, cv_fb, cv_ow0, cv_ow1, cv_ob1,
        pw0, pb0, vhw0, vhb0,
        Fc, gc, Hc, hc, Fv, gv, Pw, pbp, Vw, vbp);

    // ---- embeddings (+ fused per-node linears) ----
    embc_kernel<<<gRowsC, blk, 0, stream>>>(cf, cw0, cb0, cw1, cb1,
                                            vc_lw, vc_lb, c0b, RlC, NC);
    embv_kernel<<<gRowsV, blk, 0, stream>>>(vf, vw0, vb0, vw1, vb1,
                                            vc_rw, cv_lw, cv_lb, v0b, LsV, RlV, NV);

    // ---- block-local binned scatter (one pass over edge stream) ----
    binscatter_kernel<<<dim3(128), blk, 0, stream>>>(eic, eiv, ef, curC, curV,
                                                     bktC, bktV, nbC, nbV, E);

    // ---- conv1: v -> c ----
    aggsort_kernel<<<dim3((unsigned)nbC), blk, 0, stream>>>(cOffC, bktC, RlC, LsV, vc_ew, NC);
    consupd_kernel<<<gRowsC, blk, 0, stream>>>(RlC, c0b, cntC,
                                               Fc, vc_ow0 + 64*64, gc, vc_ob0,
                                               Hc, hc, LsC, NC);

    // ---- conv2: c -> v ----
    aggsort_kernel<<<dim3((unsigned)nbV), blk, 0, stream>>>(cOffV, bktV, RlV, LsC, cv_ew, NV);
    varupdhead_kernel<<<gRowsV, blk, 0, stream>>>(RlV, v0b, cntV,
                                                  Fv, cv_ow0 + 64*64, gv, cv_ob0,
                                                  Pw, pbp, pw1, Vw, vbp, vhw1, vhb1,
                                                  (float*)d_out, NV);
}